// Round 1
// baseline (346.779 us; speedup 1.0000x reference)
//
#include <hip/hip_runtime.h>
#include <stdint.h>

#define N_BANK 200000
#define N_PAD  201600          // 63 chunks * 3200 cols
#define NQ     2048
#define DIMD   128
#define C_IN   112
#define NCHUNK 63
#define CHUNK_COLS 3200
#define NSTEP  25              // CHUNK_COLS / 128
#define NCE    126             // NCHUNK * 2 wave-col halves
#define NC3    378             // NCE * 3

typedef short v8s __attribute__((ext_vector_type(8)));
typedef float v4f __attribute__((ext_vector_type(4)));

typedef const __attribute__((address_space(1))) uint32_t* gp1_t;
typedef __attribute__((address_space(3))) uint32_t* lp3_t;

__device__ __forceinline__ void async16(const void* g, void* l) {
  __builtin_amdgcn_global_load_lds((gp1_t)g, (lp3_t)l, 16, 0, 0);
}

__device__ __forceinline__ unsigned short f2bf(float f) {
  uint32_t u = __float_as_uint(f);
  u += 0x7fff + ((u >> 16) & 1);   // round-to-nearest-even
  return (unsigned short)(u >> 16);
}

// running top-3 insert: 3 VALU ops via med3
__device__ __forceinline__ void insert3(float& m1, float& m2, float& m3, float v) {
  m3 = __builtin_amdgcn_fmed3f(m2, m3, v);
  m2 = __builtin_amdgcn_fmed3f(m1, m2, v);
  m1 = fmaxf(m1, v);
}

// ---------------- kernel 1: patch embedding (proj + L2 norm -> bf16) --------
__global__ void emb_kernel(const float* __restrict__ fm, const float* __restrict__ pw,
                           unsigned short* __restrict__ embB) {
  int q = blockIdx.x;            // 0..2047, q = b*256 + (h*16+w)
  int b = q >> 8, p = q & 255;
  int tid = threadIdx.x;         // 128 threads = one output dim each
  __shared__ float x[C_IN];
  __shared__ float wsum[2];
  if (tid < C_IN) x[tid] = fm[(b * C_IN + tid) * 256 + p];
  __syncthreads();
  const float* row = pw + tid * C_IN;
  float dot = 0.f;
#pragma unroll
  for (int c = 0; c < C_IN; ++c) dot = fmaf(x[c], row[c], dot);
  float s = dot * dot;
#pragma unroll
  for (int off = 32; off; off >>= 1) s += __shfl_xor(s, off);
  int lane = tid & 63, wv = tid >> 6;
  if (lane == 0) wsum[wv] = s;
  __syncthreads();
  float ss = wsum[0] + wsum[1];
  float scale = 1.f / fmaxf(sqrtf(ss), 1e-12f);
  embB[q * DIMD + tid] = f2bf(dot * scale);
}

// ---------------- kernel 2: bank L2 norm -> bf16 (+ zero padding rows) ------
__global__ void bank_kernel(const float* __restrict__ bank, unsigned short* __restrict__ bankB) {
  int tid = threadIdx.x;
  int wv = tid >> 6, lane = tid & 63;
  int r = blockIdx.x * 4 + wv;          // one row per wave
  if (r >= N_PAD) return;
  uint32_t* out = (uint32_t*)bankB;     // packed 2x bf16
  if (r < N_BANK) {
    float2 v = ((const float2*)bank)[r * 64 + lane];
    float s = v.x * v.x + v.y * v.y;
#pragma unroll
    for (int off = 32; off; off >>= 1) s += __shfl_xor(s, off);
    float scale = 1.f / fmaxf(sqrtf(s), 1e-12f);
    uint32_t lo = f2bf(v.x * scale);
    uint32_t hi = f2bf(v.y * scale);
    out[r * 64 + lane] = lo | (hi << 16);
  } else {
    out[r * 64 + lane] = 0u;
  }
}

// ---------------- kernel 3: fused sims GEMM + running top-3 -----------------
// grid (16 M-tiles, 63 N-chunks), 256 threads = 4 waves in 2x2 (64x64 per wave)
__global__ __launch_bounds__(256, 2)
void sim_top3_kernel(const unsigned short* __restrict__ embB,
                     const unsigned short* __restrict__ bankB,
                     float* __restrict__ partial) {
  int mt = blockIdx.x;           // M tile (128 queries)
  int chunk = blockIdx.y;        // 3200-column bank chunk
  int q0 = mt * 128;
  int tid = threadIdx.x;
  int wv = tid >> 6, lane = tid & 63;
  int wr = wv >> 1, wc = wv & 1;       // wave row/col in 2x2
  int g = lane >> 4, c0 = lane & 15;   // frag k-group / col-class

  __shared__ __align__(16) unsigned char lds[32768];

  // ---- stage A tile (128 rows x 128 K, bf16, row-major 256B rows) ----
  {
    const char* gbase = (const char*)embB + q0 * 256;
#pragma unroll
    for (int i = 0; i < 8; ++i) {
      int off = (wv * 8 + i) * 1024 + lane * 16;
      async16(gbase + off, lds + off);
    }
  }
  __syncthreads();

  // ---- hoist A fragments to registers (64 VGPRs), persistent all steps ----
  v8s a[4][4];
#pragma unroll
  for (int fm = 0; fm < 4; ++fm)
#pragma unroll
    for (int k = 0; k < 4; ++k) {
      int row = wr * 64 + fm * 16 + c0;
      a[fm][k] = *(const v8s*)(lds + row * 256 + k * 64 + g * 16);
    }

  float m1[16], m2[16], m3[16];
#pragma unroll
  for (int t = 0; t < 16; ++t) { m1[t] = -1e30f; m2[t] = -1e30f; m3[t] = -1e30f; }

  const char* bbase = (const char*)bankB + (size_t)chunk * CHUNK_COLS * 256;
  for (int s = 0; s < NSTEP; ++s) {
    __syncthreads();                       // LDS free (A-frag reads / prev B reads done)
#pragma unroll
    for (int i = 0; i < 8; ++i) {
      int off = (wv * 8 + i) * 1024 + lane * 16;
      async16(bbase + (size_t)s * 128 * 256 + off, lds + off);
    }
    __syncthreads();                       // drains vmcnt -> B tile ready

#pragma unroll
    for (int fn = 0; fn < 4; ++fn) {
      v8s bf[4];
      int col = wc * 64 + fn * 16 + c0;
#pragma unroll
      for (int k = 0; k < 4; ++k)
        bf[k] = *(const v8s*)(lds + col * 256 + k * 64 + g * 16);
#pragma unroll
      for (int fm = 0; fm < 4; ++fm) {
        v4f acc = {0.f, 0.f, 0.f, 0.f};
#pragma unroll
        for (int k = 0; k < 4; ++k)
          acc = __builtin_amdgcn_mfma_f32_16x16x32_bf16(a[fm][k], bf[k], acc, 0, 0, 0);
#pragma unroll
        for (int j = 0; j < 4; ++j)        // C/D: row=g*4+j, col=c0 (within frag)
          insert3(m1[fm * 4 + j], m2[fm * 4 + j], m3[fm * 4 + j], acc[j]);
      }
    }
  }

  // ---- merge top-3 across the 16 col-class lanes (butterfly) ----
#pragma unroll
  for (int mask = 1; mask < 16; mask <<= 1) {
#pragma unroll
    for (int t = 0; t < 16; ++t) {
      float b1 = __shfl_xor(m1[t], mask);
      float b2 = __shfl_xor(m2[t], mask);
      float b3 = __shfl_xor(m3[t], mask);
      insert3(m1[t], m2[t], m3[t], b1);
      insert3(m1[t], m2[t], m3[t], b2);
      insert3(m1[t], m2[t], m3[t], b3);
    }
  }

  if (c0 == 0) {
    int ce = chunk * 2 + wc;               // per wave-col half partials
#pragma unroll
    for (int t = 0; t < 16; ++t) {
      int q = q0 + wr * 64 + (t >> 2) * 16 + g * 4 + (t & 3);
      partial[(ce * 3 + 0) * NQ + q] = m1[t];
      partial[(ce * 3 + 1) * NQ + q] = m2[t];
      partial[(ce * 3 + 2) * NQ + q] = m3[t];
    }
  }
}

// ---------------- kernel 4: merge partials -> dist -> top-8 mean ------------
__global__ void merge_kernel(const float* __restrict__ partial, float* __restrict__ out) {
  int b = blockIdx.x;            // image
  int tid = threadIdx.x;         // patch 0..255
  int q = b * 256 + tid;
  float m1 = -1e30f, m2 = -1e30f, m3 = -1e30f;
  for (int c = 0; c < NC3; ++c) insert3(m1, m2, m3, partial[c * NQ + q]);
  float d1 = sqrtf(fmaxf(2.f - 2.f * m1, 0.f));
  float d2 = sqrtf(fmaxf(2.f - 2.f * m2, 0.f));
  float d3 = sqrtf(fmaxf(2.f - 2.f * m3, 0.f));
  float pd = (d1 + d2 + d3) * (1.f / 3.f);

  __shared__ float vals[256];
  __shared__ float rv[256];
  __shared__ int ri[256];
  vals[tid] = pd;
  __syncthreads();
  float sum = 0.f;
  for (int iter = 0; iter < 8; ++iter) {   // k = ceil(256*0.03) = 8
    rv[tid] = vals[tid]; ri[tid] = tid;
    __syncthreads();
    for (int s = 128; s > 0; s >>= 1) {
      if (tid < s && rv[tid + s] > rv[tid]) { rv[tid] = rv[tid + s]; ri[tid] = ri[tid + s]; }
      __syncthreads();
    }
    sum += rv[0];
    if (tid == 0) vals[ri[0]] = -1e30f;
    __syncthreads();
  }
  if (tid == 0) out[b] = sum * (1.f / 8.f);
}

extern "C" void kernel_launch(void* const* d_in, const int* in_sizes, int n_in,
                              void* d_out, int out_size, void* d_ws, size_t ws_size,
                              hipStream_t stream) {
  const float* fm   = (const float*)d_in[0];   // [8,112,16,16]
  const float* pw   = (const float*)d_in[1];   // [128,112]
  const float* bank = (const float*)d_in[2];   // [200000,128]
  float* out = (float*)d_out;                  // [8]

  char* ws = (char*)d_ws;
  unsigned short* bankB = (unsigned short*)ws;                       // 51,609,600 B
  unsigned short* embB  = (unsigned short*)(ws + 51609600);          //    524,288 B
  float* partial        = (float*)(ws + 51609600 + 524288);          //  3,096,576 B

  emb_kernel<<<NQ, 128, 0, stream>>>(fm, pw, embB);
  bank_kernel<<<N_PAD / 4, 256, 0, stream>>>(bank, bankB);
  sim_top3_kernel<<<dim3(16, NCHUNK), 256, 0, stream>>>(embB, bankB, partial);
  merge_kernel<<<8, 256, 0, stream>>>(partial, out);
}

// Round 2
// 309.308 us; speedup vs baseline: 1.1211x; 1.1211x over previous
//
#include <hip/hip_runtime.h>
#include <stdint.h>

#define N_BANK 200000
#define N_PAD  201600          // 63 chunks * 3200 cols
#define NQ     2048
#define DIMD   128
#define C_IN   112
#define NCHUNK 63
#define CHUNK_COLS 3200
#define NSTEP  25              // CHUNK_COLS / 128
#define NCE    126             // NCHUNK * 2 wave-col halves
#define NC3    378             // NCE * 3

typedef short v8s __attribute__((ext_vector_type(8)));
typedef float v4f __attribute__((ext_vector_type(4)));

typedef const __attribute__((address_space(1))) uint32_t* gp1_t;
typedef __attribute__((address_space(3))) uint32_t* lp3_t;

__device__ __forceinline__ void async16(const void* g, void* l) {
  __builtin_amdgcn_global_load_lds((gp1_t)g, (lp3_t)l, 16, 0, 0);
}

__device__ __forceinline__ unsigned short f2bf(float f) {
  uint32_t u = __float_as_uint(f);
  u += 0x7fff + ((u >> 16) & 1);   // round-to-nearest-even
  return (unsigned short)(u >> 16);
}

// running top-3 insert: 3 VALU ops via med3
__device__ __forceinline__ void insert3(float& m1, float& m2, float& m3, float v) {
  m3 = __builtin_amdgcn_fmed3f(m2, m3, v);
  m2 = __builtin_amdgcn_fmed3f(m1, m2, v);
  m1 = fmaxf(m1, v);
}

// ---------------- kernel 1: patch embedding (proj + L2 norm -> bf16) --------
// Output is 16B-block swizzled within each 256B row: block j -> j ^ (row&15).
__global__ void emb_kernel(const float* __restrict__ fm, const float* __restrict__ pw,
                           unsigned short* __restrict__ embB) {
  int q = blockIdx.x;            // 0..2047, q = b*256 + (h*16+w)
  int b = q >> 8, p = q & 255;
  int tid = threadIdx.x;         // 128 threads = one output dim each
  __shared__ float x[C_IN];
  __shared__ float wsum[2];
  if (tid < C_IN) x[tid] = fm[(b * C_IN + tid) * 256 + p];
  __syncthreads();
  const float* row = pw + tid * C_IN;
  float dot = 0.f;
#pragma unroll
  for (int c = 0; c < C_IN; ++c) dot = fmaf(x[c], row[c], dot);
  float s = dot * dot;
#pragma unroll
  for (int off = 32; off; off >>= 1) s += __shfl_xor(s, off);
  int lane = tid & 63, wv = tid >> 6;
  if (lane == 0) wsum[wv] = s;
  __syncthreads();
  float ss = wsum[0] + wsum[1];
  float scale = 1.f / fmaxf(sqrtf(ss), 1e-12f);
  int j = tid >> 3, pos = tid & 7;                 // 16B block, elem within
  int sw = j ^ (q & 15);                           // bank-conflict swizzle
  embB[q * DIMD + sw * 8 + pos] = f2bf(dot * scale);
}

// ---------------- kernel 2: bank L2 norm -> bf16 (+ zero padding rows) ------
// Same 16B-block swizzle within each 256B row.
__global__ void bank_kernel(const float* __restrict__ bank, unsigned short* __restrict__ bankB) {
  int tid = threadIdx.x;
  int wv = tid >> 6, lane = tid & 63;
  int r = blockIdx.x * 4 + wv;          // one row per wave
  if (r >= N_PAD) return;
  uint32_t* out = (uint32_t*)bankB;     // packed 2x bf16
  int j = lane >> 2, w = lane & 3;      // 16B block, dword within
  int sdw = ((j ^ (r & 15)) << 2) | w;  // swizzled dword index in row
  if (r < N_BANK) {
    float2 v = ((const float2*)bank)[r * 64 + lane];
    float s = v.x * v.x + v.y * v.y;
#pragma unroll
    for (int off = 32; off; off >>= 1) s += __shfl_xor(s, off);
    float scale = 1.f / fmaxf(sqrtf(s), 1e-12f);
    uint32_t lo = f2bf(v.x * scale);
    uint32_t hi = f2bf(v.y * scale);
    out[r * 64 + sdw] = lo | (hi << 16);
  } else {
    out[r * 64 + sdw] = 0u;
  }
}

// ---------------- kernel 3: fused sims GEMM + running top-3 -----------------
// grid (16 M-tiles, 63 N-chunks), 256 threads = 4 waves in 2x2 (64x64 per wave)
__global__ __launch_bounds__(256, 2)
void sim_top3_kernel(const unsigned short* __restrict__ embB,
                     const unsigned short* __restrict__ bankB,
                     float* __restrict__ partial) {
  int mt = blockIdx.x;           // M tile (128 queries)
  int chunk = blockIdx.y;        // 3200-column bank chunk
  int q0 = mt * 128;
  int tid = threadIdx.x;
  int wv = tid >> 6, lane = tid & 63;
  int wr = wv >> 1, wc = wv & 1;       // wave row/col in 2x2
  int g = lane >> 4, c0 = lane & 15;   // frag k-group / col-class

  __shared__ __align__(16) unsigned char lds[32768];

  // ---- stage A tile (128 rows x 128 K, bf16, swizzled 256B rows) ----
  {
    const char* gbase = (const char*)embB + q0 * 256;
#pragma unroll
    for (int i = 0; i < 8; ++i) {
      int off = (wv * 8 + i) * 1024 + lane * 16;
      async16(gbase + off, lds + off);
    }
  }
  __syncthreads();

  // ---- hoist A fragments to registers (64 VGPRs), persistent all steps ----
  v8s a[4][4];
#pragma unroll
  for (int fm = 0; fm < 4; ++fm)
#pragma unroll
    for (int k = 0; k < 4; ++k) {
      int row = wr * 64 + fm * 16 + c0;
      a[fm][k] = *(const v8s*)(lds + row * 256 + (((k * 4 + g) ^ c0) << 4));
    }

  float m1[16], m2[16], m3[16];
#pragma unroll
  for (int t = 0; t < 16; ++t) { m1[t] = -1e30f; m2[t] = -1e30f; m3[t] = -1e30f; }

  const char* bbase = (const char*)bankB + (size_t)chunk * CHUNK_COLS * 256;
  for (int s = 0; s < NSTEP; ++s) {
    __syncthreads();                       // LDS free (A-frag reads / prev B reads done)
#pragma unroll
    for (int i = 0; i < 8; ++i) {
      int off = (wv * 8 + i) * 1024 + lane * 16;
      async16(bbase + (size_t)s * 128 * 256 + off, lds + off);
    }
    __syncthreads();                       // drains vmcnt -> B tile ready

#pragma unroll
    for (int fn = 0; fn < 4; ++fn) {
      v8s bf[4];
      int col = wc * 64 + fn * 16 + c0;
#pragma unroll
      for (int k = 0; k < 4; ++k)
        bf[k] = *(const v8s*)(lds + col * 256 + (((k * 4 + g) ^ c0) << 4));
#pragma unroll
      for (int fm = 0; fm < 4; ++fm) {
        v4f acc = {0.f, 0.f, 0.f, 0.f};
#pragma unroll
        for (int k = 0; k < 4; ++k)
          acc = __builtin_amdgcn_mfma_f32_16x16x32_bf16(a[fm][k], bf[k], acc, 0, 0, 0);
#pragma unroll
        for (int j = 0; j < 4; ++j)        // C/D: row=g*4+j, col=c0 (within frag)
          insert3(m1[fm * 4 + j], m2[fm * 4 + j], m3[fm * 4 + j], acc[j]);
      }
    }
  }

  // ---- merge top-3 across the 16 col-class lanes (butterfly) ----
#pragma unroll
  for (int mask = 1; mask < 16; mask <<= 1) {
#pragma unroll
    for (int t = 0; t < 16; ++t) {
      float b1 = __shfl_xor(m1[t], mask);
      float b2 = __shfl_xor(m2[t], mask);
      float b3 = __shfl_xor(m3[t], mask);
      insert3(m1[t], m2[t], m3[t], b1);
      insert3(m1[t], m2[t], m3[t], b2);
      insert3(m1[t], m2[t], m3[t], b3);
    }
  }

  if (c0 == 0) {
    int ce = chunk * 2 + wc;               // per wave-col half partials
#pragma unroll
    for (int t = 0; t < 16; ++t) {
      int q = q0 + wr * 64 + (t >> 2) * 16 + g * 4 + (t & 3);
      float* dst = partial + (size_t)q * NC3 + ce * 3;   // query-major
      dst[0] = m1[t];
      dst[1] = m2[t];
      dst[2] = m3[t];
    }
  }
}

// ---------------- kernel 4a: per-query merge of 378 partials -> patch dist --
// one wave per query; coalesced scan + butterfly top-3 merge
__global__ void merge1_kernel(const float* __restrict__ partial, float* __restrict__ pd) {
  int q = (blockIdx.x * blockDim.x + threadIdx.x) >> 6;
  int lane = threadIdx.x & 63;
  const float* src = partial + (size_t)q * NC3;
  float m1 = -1e30f, m2 = -1e30f, m3 = -1e30f;
  for (int c = lane; c < NC3; c += 64) insert3(m1, m2, m3, src[c]);
#pragma unroll
  for (int mask = 32; mask; mask >>= 1) {
    float b1 = __shfl_xor(m1, mask);
    float b2 = __shfl_xor(m2, mask);
    float b3 = __shfl_xor(m3, mask);
    insert3(m1, m2, m3, b1);
    insert3(m1, m2, m3, b2);
    insert3(m1, m2, m3, b3);
  }
  if (lane == 0) {
    float d1 = sqrtf(fmaxf(2.f - 2.f * m1, 0.f));
    float d2 = sqrtf(fmaxf(2.f - 2.f * m2, 0.f));
    float d3 = sqrtf(fmaxf(2.f - 2.f * m3, 0.f));
    pd[q] = (d1 + d2 + d3) * (1.f / 3.f);
  }
}

// ---------------- kernel 4b: per-image top-8 mean ---------------------------
__global__ void merge2_kernel(const float* __restrict__ pd, float* __restrict__ out) {
  int b = blockIdx.x;            // image
  int tid = threadIdx.x;         // patch 0..255
  __shared__ float vals[256];
  __shared__ float rv[256];
  __shared__ int ri[256];
  vals[tid] = pd[b * 256 + tid];
  __syncthreads();
  float sum = 0.f;
  for (int iter = 0; iter < 8; ++iter) {   // k = ceil(256*0.03) = 8
    rv[tid] = vals[tid]; ri[tid] = tid;
    __syncthreads();
    for (int s = 128; s > 0; s >>= 1) {
      if (tid < s && rv[tid + s] > rv[tid]) { rv[tid] = rv[tid + s]; ri[tid] = ri[tid + s]; }
      __syncthreads();
    }
    sum += rv[0];
    if (tid == 0) vals[ri[0]] = -1e30f;
    __syncthreads();
  }
  if (tid == 0) out[b] = sum * (1.f / 8.f);
}

extern "C" void kernel_launch(void* const* d_in, const int* in_sizes, int n_in,
                              void* d_out, int out_size, void* d_ws, size_t ws_size,
                              hipStream_t stream) {
  const float* fm   = (const float*)d_in[0];   // [8,112,16,16]
  const float* pw   = (const float*)d_in[1];   // [128,112]
  const float* bank = (const float*)d_in[2];   // [200000,128]
  float* out = (float*)d_out;                  // [8]

  char* ws = (char*)d_ws;
  unsigned short* bankB = (unsigned short*)ws;                       // 51,609,600 B
  unsigned short* embB  = (unsigned short*)(ws + 51609600);          //    524,288 B
  float* partial        = (float*)(ws + 51609600 + 524288);          //  3,096,576 B
  float* pd             = (float*)(ws + 51609600 + 524288 + 3096576);//      8,192 B

  emb_kernel<<<NQ, 128, 0, stream>>>(fm, pw, embB);
  bank_kernel<<<N_PAD / 4, 256, 0, stream>>>(bank, bankB);
  sim_top3_kernel<<<dim3(16, NCHUNK), 256, 0, stream>>>(embB, bankB, partial);
  merge1_kernel<<<NQ / 4, 256, 0, stream>>>(partial, pd);
  merge2_kernel<<<8, 256, 0, stream>>>(pd, out);
}